// Round 4
// baseline (1567.562 us; speedup 1.0000x reference)
//
#include <hip/hip_runtime.h>
#include <cstdint>

typedef short short8 __attribute__((ext_vector_type(8)));
typedef float floatx4 __attribute__((ext_vector_type(4)));

constexpr int NU = 200000;   // N_USER
constexpr int NI = 100000;   // N_ITEM
constexpr int NEDGE = 1000000;
constexpr int HD = 128;
constexpr int HH = HD * HD;
constexpr int BUKW = 128;    // nodes per bucket (k_part/k_place)

// ---- bf16 bit helpers ----
__device__ __forceinline__ float bits2f(short s) {
    return __uint_as_float(((unsigned int)(unsigned short)s) << 16);
}
__device__ __forceinline__ short f2bits(float f) {
    unsigned int u = __float_as_uint(f);
    unsigned int lsb = (u >> 16) & 1u;
    u += 0x7fffu + lsb;   // round-to-nearest-even
    return (short)(u >> 16);
}

// ================= CSR build =================
__global__ void k_hist(const int* __restrict__ dst, int* __restrict__ deg, int E) {
    int e = blockIdx.x * 256 + threadIdx.x;
    if (e < E) atomicAdd(&deg[dst[e]], 1);
}

__global__ void k_block_sums(const int* __restrict__ deg, int* __restrict__ bsum, int N) {
    __shared__ int s[1024];
    int t = threadIdx.x;
    int i = blockIdx.x * 1024 + t;
    s[t] = (i < N) ? deg[i] : 0;
    __syncthreads();
    for (int d = 512; d > 0; d >>= 1) {
        if (t < d) s[t] += s[t + d];
        __syncthreads();
    }
    if (t == 0) bsum[blockIdx.x] = s[0];
}

__global__ void k_scan_bsums(const int* __restrict__ bsum, int* __restrict__ boff,
                             int* __restrict__ off, int nb, int N) {
    __shared__ int s[1024];
    int t = threadIdx.x;
    int v = (t < nb) ? bsum[t] : 0;
    s[t] = v;
    __syncthreads();
    for (int d = 1; d < 1024; d <<= 1) {
        int u = (t >= d) ? s[t - d] : 0;
        __syncthreads();
        s[t] += u;
        __syncthreads();
    }
    if (t < nb) boff[t] = s[t] - v;     // exclusive block offsets
    if (t == nb - 1) off[N] = s[t];     // total
}

__global__ void k_scan_write(const int* __restrict__ deg, const int* __restrict__ boff,
                             int* __restrict__ off, int N) {
    __shared__ int s[1024];
    int t = threadIdx.x;
    int i = blockIdx.x * 1024 + t;
    int v = (i < N) ? deg[i] : 0;
    s[t] = v;
    __syncthreads();
    for (int d = 1; d < 1024; d <<= 1) {
        int u = (t >= d) ? s[t - d] : 0;
        __syncthreads();
        s[t] += u;
        __syncthreads();
    }
    if (i < N) off[i] = boff[blockIdx.x] + s[t] - v;
}

// bucket cursors seeded from off[] at stride BUKW
__global__ void k_initcur(const int* __restrict__ off, int* __restrict__ bcur, int nbuk) {
    int b = blockIdx.x * 256 + threadIdx.x;
    if (b < nbuk) bcur[b] = off[b * BUKW];
}

// Pass A: partition (src,dst) pairs into per-bucket append streams.
// ~nbuk open cache lines (L2-resident) instead of fully random 4B scatter.
__global__ void k_part(const int* __restrict__ src, const int* __restrict__ dst,
                       int* __restrict__ bcur, int2* __restrict__ pairs, int E) {
    int e = blockIdx.x * 256 + threadIdx.x;
    if (e < E) {
        int d = dst[e];
        int pos = atomicAdd(&bcur[d >> 7], 1);   // BUKW = 128
        pairs[pos] = make_int2(src[e], d);
    }
}

// Pass B: one block per bucket; LDS cursors (block owns ALL edges of its nodes);
// esrc writes confined to the bucket's contiguous segment -> written once.
__global__ __launch_bounds__(256) void k_place(const int2* __restrict__ pairs,
                                               const int* __restrict__ off,
                                               int* __restrict__ esrc, int N) {
    __shared__ int scur[BUKW];
    int b = blockIdx.x;
    int n0 = b * BUKW;
    int nend = min(n0 + BUKW, N);
    int t = threadIdx.x;
    if (t < BUKW) scur[t] = (n0 + t < nend) ? off[n0 + t] : 0;
    __syncthreads();
    int base = off[n0];
    int end = off[nend];
    for (int e = base + t; e < end; e += 256) {
        int2 p = pairs[e];
        int pos = atomicAdd(&scur[p.y - n0], 1);
        esrc[pos] = p.x;
    }
}

// ================= mean aggregation (bf16 gather over CSR) =================
__global__ __launch_bounds__(256) void k_agg(const short* __restrict__ X,
                                             const int* __restrict__ off,
                                             const int* __restrict__ esrc,
                                             short* __restrict__ agg, int N) {
    int t = threadIdx.x;
    int node = blockIdx.x * 16 + (t >> 4);
    int ln = t & 15;
    if (node >= N) return;
    int s = off[node], e = off[node + 1];
    float a[8] = {0.f, 0.f, 0.f, 0.f, 0.f, 0.f, 0.f, 0.f};
    for (int j = s; j < e; ++j) {
        const short8 v = *(const short8*)(X + (size_t)esrc[j] * HD + ln * 8);
#pragma unroll
        for (int i = 0; i < 8; ++i) a[i] += bits2f(v[i]);
    }
    int d = e - s;
    float inv = 1.f / (float)(d > 0 ? d : 1);
    short8 o;
#pragma unroll
    for (int i = 0; i < 8; ++i) o[i] = f2bits(a[i] * inv);
    *(short8*)(agg + (size_t)node * HD + ln * 8) = o;
}

// ================= weight pack (fp32 -> bf16 fragment order) =================
__global__ void k_pack(short* __restrict__ dst, const float* __restrict__ A,
                       const float* __restrict__ B, const float* __restrict__ B2,
                       int KA, int KBr, int NCOL) {
    int l = threadIdx.x;
    int kbt = (KA + KBr) >> 5;
    int nt = blockIdx.x / kbt;
    int kb = blockIdx.x % kbt;
    int col = nt * 16 + (l & 15);
    int k0 = kb * 32 + (l >> 4) * 8;
    short8 o;
#pragma unroll
    for (int j = 0; j < 8; ++j) {
        int k = k0 + j;
        float f;
        if (k < KA) {
            f = A[(size_t)k * NCOL + col];
        } else {
            int k2 = k - KA;
            f = B[(size_t)k2 * NCOL + col];
            if (B2) f += B2[(size_t)k2 * NCOL + col];
        }
        o[j] = f2bits(f);
    }
    *(short8*)(dst + ((size_t)blockIdx.x * 64 + l) * 8) = o;
}

__global__ void k_addbias(float* __restrict__ dst, const float* __restrict__ a,
                          const float* __restrict__ b) {
    int i = threadIdx.x;
    dst[i] = a[i] + b[i];
}

// ================= MFMA GEMM v2: 32 rows/wave =================
// C[M, NT*16] = [A1 | A2] @ Wp(packed bf16) (+bias) (+=C) (leaky)
// block = 4 waves, each wave owns a 32-row strip (2 x 16-row A-frag sets),
// so each B fragment load feeds TWO MFMAs (B-issue was the v1 bottleneck).
// A-frag: lane l holds A[row=l&15][k=(l>>4)*8+j]; B pre-packed; C/D verified m89/m91.
template <int KB1, int KB2, bool AF32, bool ACCUM, bool LEAKY, bool OUTF32, int NT>
__global__ __launch_bounds__(256) void k_mm(const void* __restrict__ A1v,
                                            const void* __restrict__ A2v,
                                            const short* __restrict__ Wp,
                                            const float* __restrict__ bias,
                                            void* __restrict__ Cv, int M) {
    constexpr int KBT = KB1 + KB2;
    const int lane = threadIdx.x & 63;
    const int wv = threadIdx.x >> 6;
    const int r0 = blockIdx.x * 128 + wv * 32;

    const int ksub = (lane >> 4) * 8;
    short8 afrag[2][KBT];
#pragma unroll
    for (int h = 0; h < 2; ++h) {
        int ar = r0 + h * 16 + (lane & 15);
        if (ar >= M) ar = M - 1;       // clamp: only pollutes masked-out C rows
        if constexpr (AF32) {
            const float* p = (const float*)A1v + (size_t)ar * (KB1 * 32) + ksub;
#pragma unroll
            for (int kb = 0; kb < KB1; ++kb) {
                short8 f;
#pragma unroll
                for (int j = 0; j < 8; ++j) f[j] = f2bits(p[kb * 32 + j]);
                afrag[h][kb] = f;
            }
        } else {
            const short* p = (const short*)A1v + (size_t)ar * (KB1 * 32) + ksub;
#pragma unroll
            for (int kb = 0; kb < KB1; ++kb) afrag[h][kb] = *(const short8*)(p + kb * 32);
        }
        if constexpr (KB2 > 0) {
            const short* p = (const short*)A2v + (size_t)ar * (KB2 * 32) + ksub;
#pragma unroll
            for (int kb = 0; kb < KB2; ++kb) afrag[h][KB1 + kb] = *(const short8*)(p + kb * 32);
        }
    }

    floatx4 acc[2][NT];
#pragma unroll
    for (int h = 0; h < 2; ++h)
#pragma unroll
        for (int nt = 0; nt < NT; ++nt) acc[h][nt] = (floatx4){0.f, 0.f, 0.f, 0.f};

    const short8* wp = (const short8*)Wp + lane;
#pragma unroll
    for (int nt = 0; nt < NT; ++nt) {
#pragma unroll
        for (int kb = 0; kb < KBT; ++kb) {
            short8 b = wp[(nt * KBT + kb) * 64];
            acc[0][nt] = __builtin_amdgcn_mfma_f32_16x16x32_bf16(afrag[0][kb], b, acc[0][nt], 0, 0, 0);
            acc[1][nt] = __builtin_amdgcn_mfma_f32_16x16x32_bf16(afrag[1][kb], b, acc[1][nt], 0, 0, 0);
        }
    }

    const int col = lane & 15;
#pragma unroll
    for (int h = 0; h < 2; ++h) {
        const int rbase = r0 + h * 16 + (lane >> 4) * 4;
#pragma unroll
        for (int nt = 0; nt < NT; ++nt) {
            float bv = bias ? bias[nt * 16 + col] : 0.f;
#pragma unroll
            for (int r = 0; r < 4; ++r) {
                int row = rbase + r;
                if (row < M) {
                    float v = acc[h][nt][r] + bv;
                    if constexpr (OUTF32) {
                        float* cp = (float*)Cv + (size_t)row * (NT * 16) + nt * 16 + col;
                        if constexpr (ACCUM) v += *cp;
                        if constexpr (LEAKY) v = (v >= 0.f) ? v : 0.01f * v;
                        *cp = v;
                    } else {
                        short* cp = (short*)Cv + (size_t)row * (NT * 16) + nt * 16 + col;
                        if constexpr (ACCUM) v += bits2f(*cp);
                        if constexpr (LEAKY) v = (v >= 0.f) ? v : 0.01f * v;
                        *cp = f2bits(v);
                    }
                }
            }
        }
    }
}

// ================= launch =================
extern "C" void kernel_launch(void* const* d_in, const int* in_sizes, int n_in,
                              void* d_out, int out_size, void* d_ws, size_t ws_size,
                              hipStream_t stream) {
    const float* x_user    = (const float*)d_in[0];
    const float* x_item    = (const float*)d_in[1];
    const int* src_rates   = (const int*)d_in[2];
    const int* dst_rates   = (const int*)d_in[3];
    const int* src_rated   = (const int*)d_in[4];
    const int* dst_rated   = (const int*)d_in[5];
    const int* src_fol     = (const int*)d_in[6];
    const int* dst_fol     = (const int*)d_in[7];
    const float* W_in_user = (const float*)d_in[8];
    const float* b_in_user = (const float*)d_in[9];
    const float* W_in_item = (const float*)d_in[10];
    const float* b_in_item = (const float*)d_in[11];
    const float* Wl_rates  = (const float*)d_in[12];
    const float* bl_rates  = (const float*)d_in[13];
    const float* Wr_rates  = (const float*)d_in[14];
    const float* Wl_rated  = (const float*)d_in[15];
    const float* bl_rated  = (const float*)d_in[16];
    const float* Wr_rated  = (const float*)d_in[17];
    const float* Wl_fol    = (const float*)d_in[18];
    const float* bl_fol    = (const float*)d_in[19];
    const float* Wr_fol    = (const float*)d_in[20];
    const float* W_out     = (const float*)d_in[21];
    const float* b_out     = (const float*)d_in[22];
    float* out = (float*)d_out;

    char* w = (char*)d_ws;
    size_t used = 0;
    auto alloc = [&](size_t bytes) -> void* {
        void* p = w + used;
        used += (bytes + 255) & ~(size_t)255;
        return p;
    };
    short* hu_a = (short*)alloc((size_t)NU * HD * 2);
    short* hu_b = (short*)alloc((size_t)NU * HD * 2);
    short* hi_a = (short*)alloc((size_t)NI * HD * 2);
    short* hi_b = (short*)alloc((size_t)NI * HD * 2);
    short* agg  = (short*)alloc((size_t)NU * HD * 2);

    int* deg_rates  = (int*)alloc((size_t)NI * 4);
    int* off_rates  = (int*)alloc((size_t)(NI + 1) * 4);
    int* esrc_rates = (int*)alloc((size_t)NEDGE * 4);
    int* deg_rated  = (int*)alloc((size_t)NU * 4);
    int* off_rated  = (int*)alloc((size_t)(NU + 1) * 4);
    int* esrc_rated = (int*)alloc((size_t)NEDGE * 4);
    int* deg_fol    = (int*)alloc((size_t)NU * 4);
    int* off_fol    = (int*)alloc((size_t)(NU + 1) * 4);
    int* esrc_fol   = (int*)alloc((size_t)NEDGE * 4);
    int2* pairs     = (int2*)alloc((size_t)NEDGE * 8);   // shared across graphs
    int* bcur       = (int*)alloc(((NU + BUKW - 1) / BUKW) * 4);
    int* bsum = (int*)alloc(1024 * 4);
    int* boff = (int*)alloc(1024 * 4);

    short* pWu      = (short*)alloc(8 * 2 * 64 * 8 * 2);
    short* pWi      = (short*)alloc(8 * 4 * 64 * 8 * 2);
    short* pRates0  = (short*)alloc(8 * 8 * 64 * 8 * 2);
    short* pRates1  = (short*)alloc(8 * 8 * 64 * 8 * 2);
    short* pRated0  = (short*)alloc(8 * 8 * 64 * 8 * 2);
    short* pRated1  = (short*)alloc(8 * 8 * 64 * 8 * 2);
    short* pFol0    = (short*)alloc(8 * 4 * 64 * 8 * 2);
    short* pFol1    = (short*)alloc(8 * 4 * 64 * 8 * 2);
    short* pHead    = (short*)alloc(1 * 4 * 64 * 8 * 2);
    float* bSum0    = (float*)alloc(128 * 4);
    float* bSum1    = (float*)alloc(128 * 4);
    if (used > ws_size) return;   // diagnostic signature: output stays zero

    auto build_csr = [&](const int* dstA, const int* srcA, int N, int* deg, int* off,
                         int* esrc) {
        hipMemsetAsync(deg, 0, (size_t)N * 4, stream);
        k_hist<<<(NEDGE + 255) / 256, 256, 0, stream>>>(dstA, deg, NEDGE);
        int nb = (N + 1023) / 1024;
        k_block_sums<<<nb, 1024, 0, stream>>>(deg, bsum, N);
        k_scan_bsums<<<1, 1024, 0, stream>>>(bsum, boff, off, nb, N);
        k_scan_write<<<nb, 1024, 0, stream>>>(deg, boff, off, N);
        int nbuk = (N + BUKW - 1) / BUKW;
        k_initcur<<<(nbuk + 255) / 256, 256, 0, stream>>>(off, bcur, nbuk);
        k_part<<<(NEDGE + 255) / 256, 256, 0, stream>>>(srcA, dstA, bcur, pairs, NEDGE);
        k_place<<<nbuk, 256, 0, stream>>>(pairs, off, esrc, N);
    };

    build_csr(dst_rates, src_rates, NI, deg_rates, off_rates, esrc_rates);
    build_csr(dst_rated, src_rated, NU, deg_rated, off_rated, esrc_rated);
    build_csr(dst_fol,   src_fol,   NU, deg_fol,   off_fol,   esrc_fol);

    // ---- weight packing ----
    k_pack<<<16, 64, 0, stream>>>(pWu, W_in_user, nullptr, nullptr, 64, 0, 128);
    k_pack<<<32, 64, 0, stream>>>(pWi, W_in_item, nullptr, nullptr, 128, 0, 128);
    k_pack<<<64, 64, 0, stream>>>(pRates0, Wl_rates,      Wr_rates,      nullptr,       128, 128, 128);
    k_pack<<<64, 64, 0, stream>>>(pRates1, Wl_rates + HH, Wr_rates + HH, nullptr,       128, 128, 128);
    k_pack<<<64, 64, 0, stream>>>(pRated0, Wl_rated,      Wr_rated,      Wr_fol,        128, 128, 128);
    k_pack<<<64, 64, 0, stream>>>(pRated1, Wl_rated + HH, Wr_rated + HH, Wr_fol + HH,   128, 128, 128);
    k_pack<<<32, 64, 0, stream>>>(pFol0, Wl_fol,      nullptr, nullptr, 128, 0, 128);
    k_pack<<<32, 64, 0, stream>>>(pFol1, Wl_fol + HH, nullptr, nullptr, 128, 0, 128);
    k_pack<<<4, 64, 0, stream>>>(pHead, W_out, nullptr, nullptr, 128, 0, 16);
    k_addbias<<<1, 128, 0, stream>>>(bSum0, bl_rated,       bl_fol);
    k_addbias<<<1, 128, 0, stream>>>(bSum1, bl_rated + 128, bl_fol + 128);

    const int gU = (NU + 127) / 128;   // 1563
    const int gI = (NI + 127) / 128;   // 782
    const int gaU = (NU + 15) / 16;
    const int gaI = (NI + 15) / 16;

    // ---- input projections (fp32 A) ----
    k_mm<2, 0, true, false, false, false, 8><<<gU, 256, 0, stream>>>(
        x_user, nullptr, pWu, b_in_user, hu_a, NU);
    k_mm<4, 0, true, false, false, false, 8><<<gI, 256, 0, stream>>>(
        x_item, nullptr, pWi, b_in_item, hi_a, NI);

    // ---- layer 0 (leaky) ----
    k_agg<<<gaI, 256, 0, stream>>>(hu_a, off_rates, esrc_rates, agg, NI);
    k_mm<4, 4, false, false, true, false, 8><<<gI, 256, 0, stream>>>(
        agg, hi_a, pRates0, bl_rates, hi_b, NI);
    k_agg<<<gaU, 256, 0, stream>>>(hi_a, off_rated, esrc_rated, agg, NU);
    k_mm<4, 4, false, false, false, false, 8><<<gU, 256, 0, stream>>>(
        agg, hu_a, pRated0, bSum0, hu_b, NU);
    k_agg<<<gaU, 256, 0, stream>>>(hu_a, off_fol, esrc_fol, agg, NU);
    k_mm<4, 0, false, true, true, false, 8><<<gU, 256, 0, stream>>>(
        agg, nullptr, pFol0, nullptr, hu_b, NU);

    // ---- layer 1 (no leaky) ----
    k_agg<<<gaI, 256, 0, stream>>>(hu_b, off_rates, esrc_rates, agg, NI);
    k_mm<4, 4, false, false, false, false, 8><<<gI, 256, 0, stream>>>(
        agg, hi_b, pRates1, bl_rates + 128, hi_a, NI);
    k_agg<<<gaU, 256, 0, stream>>>(hi_b, off_rated, esrc_rated, agg, NU);
    k_mm<4, 4, false, false, false, false, 8><<<gU, 256, 0, stream>>>(
        agg, hu_b, pRated1, bSum1, hu_a, NU);
    k_agg<<<gaU, 256, 0, stream>>>(hu_b, off_fol, esrc_fol, agg, NU);
    k_mm<4, 0, false, true, false, false, 8><<<gU, 256, 0, stream>>>(
        agg, nullptr, pFol1, nullptr, hu_a, NU);

    // ---- head (fp32 out) ----
    k_mm<4, 0, false, false, false, true, 1><<<gU, 256, 0, stream>>>(
        hu_a, nullptr, pHead, b_out, out, NU);
}

// Round 5
// 1032.109 us; speedup vs baseline: 1.5188x; 1.5188x over previous
//
#include <hip/hip_runtime.h>
#include <cstdint>

typedef short short8 __attribute__((ext_vector_type(8)));
typedef float floatx4 __attribute__((ext_vector_type(4)));

constexpr int NU = 200000;   // N_USER
constexpr int NI = 100000;   // N_ITEM
constexpr int NEDGE = 1000000;
constexpr int HD = 128;
constexpr int HH = HD * HD;

// ---- bf16 bit helpers ----
__device__ __forceinline__ float bits2f(short s) {
    return __uint_as_float(((unsigned int)(unsigned short)s) << 16);
}
__device__ __forceinline__ short f2bits(float f) {
    unsigned int u = __float_as_uint(f);
    unsigned int lsb = (u >> 16) & 1u;
    u += 0x7fffu + lsb;   // round-to-nearest-even
    return (short)(u >> 16);
}

// ================= CSR build (round-3 proven path) =================
__global__ void k_hist(const int* __restrict__ dst, int* __restrict__ deg, int E) {
    int e = blockIdx.x * 256 + threadIdx.x;
    if (e < E) atomicAdd(&deg[dst[e]], 1);
}

__global__ void k_block_sums(const int* __restrict__ deg, int* __restrict__ bsum, int N) {
    __shared__ int s[1024];
    int t = threadIdx.x;
    int i = blockIdx.x * 1024 + t;
    s[t] = (i < N) ? deg[i] : 0;
    __syncthreads();
    for (int d = 512; d > 0; d >>= 1) {
        if (t < d) s[t] += s[t + d];
        __syncthreads();
    }
    if (t == 0) bsum[blockIdx.x] = s[0];
}

__global__ void k_scan_bsums(const int* __restrict__ bsum, int* __restrict__ boff,
                             int* __restrict__ off, int nb, int N) {
    __shared__ int s[1024];
    int t = threadIdx.x;
    int v = (t < nb) ? bsum[t] : 0;
    s[t] = v;
    __syncthreads();
    for (int d = 1; d < 1024; d <<= 1) {
        int u = (t >= d) ? s[t - d] : 0;
        __syncthreads();
        s[t] += u;
        __syncthreads();
    }
    if (t < nb) boff[t] = s[t] - v;     // exclusive block offsets
    if (t == nb - 1) off[N] = s[t];     // total
}

__global__ void k_scan_write(const int* __restrict__ deg, const int* __restrict__ boff,
                             int* __restrict__ off, int N) {
    __shared__ int s[1024];
    int t = threadIdx.x;
    int i = blockIdx.x * 1024 + t;
    int v = (i < N) ? deg[i] : 0;
    s[t] = v;
    __syncthreads();
    for (int d = 1; d < 1024; d <<= 1) {
        int u = (t >= d) ? s[t - d] : 0;
        __syncthreads();
        s[t] += u;
        __syncthreads();
    }
    if (i < N) off[i] = boff[blockIdx.x] + s[t] - v;
}

// low-contention scatter fill (73 us measured r3; k_part bucket variant was 3x WORSE)
__global__ void k_fill(const int* __restrict__ src, const int* __restrict__ dst,
                       int* __restrict__ cur, int* __restrict__ esrc, int E) {
    int e = blockIdx.x * 256 + threadIdx.x;
    if (e < E) {
        int pos = atomicAdd(&cur[dst[e]], 1);
        esrc[pos] = src[e];
    }
}

// ================= weight pack (fp32 -> bf16 fragment order) =================
__global__ void k_pack(short* __restrict__ dst, const float* __restrict__ A,
                       const float* __restrict__ B, const float* __restrict__ B2,
                       int KA, int KBr, int NCOL) {
    int l = threadIdx.x;
    int kbt = (KA + KBr) >> 5;
    int nt = blockIdx.x / kbt;
    int kb = blockIdx.x % kbt;
    int col = nt * 16 + (l & 15);
    int k0 = kb * 32 + (l >> 4) * 8;
    short8 o;
#pragma unroll
    for (int j = 0; j < 8; ++j) {
        int k = k0 + j;
        float f;
        if (k < KA) {
            f = A[(size_t)k * NCOL + col];
        } else {
            int k2 = k - KA;
            f = B[(size_t)k2 * NCOL + col];
            if (B2) f += B2[(size_t)k2 * NCOL + col];
        }
        o[j] = f2bits(f);
    }
    *(short8*)(dst + ((size_t)blockIdx.x * 64 + l) * 8) = o;
}

__global__ void k_addbias(float* __restrict__ dst, const float* __restrict__ a,
                          const float* __restrict__ b) {
    int i = threadIdx.x;
    dst[i] = a[i] + b[i];
}

// ================= fused SAGE: gather-mean + MFMA GEMM =================
// C[M,128] = mean_{nbr} Xsrc[nbr] @ Wl  (+ A2 @ Wr)  (+bias) (+=C) (leaky)
// block = 4 waves, each wave owns a 16-row strip. The A-fragment for the
// gather side is built on the fly: 4 lanes per row (lane&15 = row) each
// accumulate 4x8 contiguous bf16 cols of the row's neighbors in fp32.
// B pre-packed fragment-order; C/D mapping verified m89/m91.
template <int KB2, bool ACCUM, bool LEAKY>
__global__ __launch_bounds__(256) void k_sage(const short* __restrict__ Xsrc,
                                              const short* __restrict__ A2,
                                              const int* __restrict__ off,
                                              const int* __restrict__ esrc,
                                              const short* __restrict__ Wp,
                                              const float* __restrict__ bias,
                                              short* __restrict__ C, int M) {
    constexpr int KBT = 4 + KB2;   // gather side is always K=128 (4 kb)
    const int lane = threadIdx.x & 63;
    const int wv = threadIdx.x >> 6;
    const int r0 = blockIdx.x * 64 + wv * 16;

    int ar = r0 + (lane & 15);
    if (ar >= M) ar = M - 1;       // clamp: only pollutes masked-out C rows
    const int ksub = (lane >> 4) * 8;

    // ---- gather-mean into fp32, then convert to A-fragments ----
    float macc[4][8];
#pragma unroll
    for (int kb = 0; kb < 4; ++kb)
#pragma unroll
        for (int i = 0; i < 8; ++i) macc[kb][i] = 0.f;

    const int s = off[ar], e = off[ar + 1];
    for (int j = s; j < e; ++j) {
        const short* xp = Xsrc + (size_t)esrc[j] * HD + ksub;
#pragma unroll
        for (int kb = 0; kb < 4; ++kb) {
            short8 v = *(const short8*)(xp + kb * 32);
#pragma unroll
            for (int i = 0; i < 8; ++i) macc[kb][i] += bits2f(v[i]);
        }
    }
    const int d = e - s;
    const float inv = 1.f / (float)(d > 0 ? d : 1);

    short8 afrag[KBT];
#pragma unroll
    for (int kb = 0; kb < 4; ++kb) {
        short8 f;
#pragma unroll
        for (int i = 0; i < 8; ++i) f[i] = f2bits(macc[kb][i] * inv);
        afrag[kb] = f;
    }
    if constexpr (KB2 > 0) {
        const short* p = A2 + (size_t)ar * (KB2 * 32) + ksub;
#pragma unroll
        for (int kb = 0; kb < KB2; ++kb) afrag[4 + kb] = *(const short8*)(p + kb * 32);
    }

    // ---- MFMA over 8 column tiles ----
    floatx4 acc[8];
#pragma unroll
    for (int nt = 0; nt < 8; ++nt) acc[nt] = (floatx4){0.f, 0.f, 0.f, 0.f};

    const short8* wp = (const short8*)Wp + lane;
#pragma unroll
    for (int nt = 0; nt < 8; ++nt) {
#pragma unroll
        for (int kb = 0; kb < KBT; ++kb) {
            short8 b = wp[(nt * KBT + kb) * 64];
            acc[nt] = __builtin_amdgcn_mfma_f32_16x16x32_bf16(afrag[kb], b, acc[nt], 0, 0, 0);
        }
    }

    // ---- epilogue ----
    const int col = lane & 15;
    const int rbase = r0 + (lane >> 4) * 4;
#pragma unroll
    for (int nt = 0; nt < 8; ++nt) {
        float bv = bias ? bias[nt * 16 + col] : 0.f;
#pragma unroll
        for (int r = 0; r < 4; ++r) {
            int row = rbase + r;
            if (row < M) {
                short* cp = C + (size_t)row * HD + nt * 16 + col;
                float v = acc[nt][r] + bv;
                if constexpr (ACCUM) v += bits2f(*cp);
                if constexpr (LEAKY) v = (v >= 0.f) ? v : 0.01f * v;
                *cp = f2bits(v);
            }
        }
    }
}

// ================= plain MFMA GEMM v2 (proj/head): 32 rows/wave =================
template <int KB1, bool AF32, bool OUTF32, int NT>
__global__ __launch_bounds__(256) void k_mm(const void* __restrict__ A1v,
                                            const short* __restrict__ Wp,
                                            const float* __restrict__ bias,
                                            void* __restrict__ Cv, int M) {
    constexpr int KBT = KB1;
    const int lane = threadIdx.x & 63;
    const int wv = threadIdx.x >> 6;
    const int r0 = blockIdx.x * 128 + wv * 32;

    const int ksub = (lane >> 4) * 8;
    short8 afrag[2][KBT];
#pragma unroll
    for (int h = 0; h < 2; ++h) {
        int ar = r0 + h * 16 + (lane & 15);
        if (ar >= M) ar = M - 1;
        if constexpr (AF32) {
            const float* p = (const float*)A1v + (size_t)ar * (KB1 * 32) + ksub;
#pragma unroll
            for (int kb = 0; kb < KB1; ++kb) {
                short8 f;
#pragma unroll
                for (int j = 0; j < 8; ++j) f[j] = f2bits(p[kb * 32 + j]);
                afrag[h][kb] = f;
            }
        } else {
            const short* p = (const short*)A1v + (size_t)ar * (KB1 * 32) + ksub;
#pragma unroll
            for (int kb = 0; kb < KB1; ++kb) afrag[h][kb] = *(const short8*)(p + kb * 32);
        }
    }

    floatx4 acc[2][NT];
#pragma unroll
    for (int h = 0; h < 2; ++h)
#pragma unroll
        for (int nt = 0; nt < NT; ++nt) acc[h][nt] = (floatx4){0.f, 0.f, 0.f, 0.f};

    const short8* wp = (const short8*)Wp + lane;
#pragma unroll
    for (int nt = 0; nt < NT; ++nt) {
#pragma unroll
        for (int kb = 0; kb < KBT; ++kb) {
            short8 b = wp[(nt * KBT + kb) * 64];
            acc[0][nt] = __builtin_amdgcn_mfma_f32_16x16x32_bf16(afrag[0][kb], b, acc[0][nt], 0, 0, 0);
            acc[1][nt] = __builtin_amdgcn_mfma_f32_16x16x32_bf16(afrag[1][kb], b, acc[1][nt], 0, 0, 0);
        }
    }

    const int col = lane & 15;
#pragma unroll
    for (int h = 0; h < 2; ++h) {
        const int rbase = r0 + h * 16 + (lane >> 4) * 4;
#pragma unroll
        for (int nt = 0; nt < NT; ++nt) {
            float bv = bias ? bias[nt * 16 + col] : 0.f;
#pragma unroll
            for (int r = 0; r < 4; ++r) {
                int row = rbase + r;
                if (row < M) {
                    float v = acc[h][nt][r] + bv;
                    if constexpr (OUTF32) {
                        ((float*)Cv)[(size_t)row * (NT * 16) + nt * 16 + col] = v;
                    } else {
                        ((short*)Cv)[(size_t)row * (NT * 16) + nt * 16 + col] = f2bits(v);
                    }
                }
            }
        }
    }
}

// ================= launch =================
extern "C" void kernel_launch(void* const* d_in, const int* in_sizes, int n_in,
                              void* d_out, int out_size, void* d_ws, size_t ws_size,
                              hipStream_t stream) {
    const float* x_user    = (const float*)d_in[0];
    const float* x_item    = (const float*)d_in[1];
    const int* src_rates   = (const int*)d_in[2];
    const int* dst_rates   = (const int*)d_in[3];
    const int* src_rated   = (const int*)d_in[4];
    const int* dst_rated   = (const int*)d_in[5];
    const int* src_fol     = (const int*)d_in[6];
    const int* dst_fol     = (const int*)d_in[7];
    const float* W_in_user = (const float*)d_in[8];
    const float* b_in_user = (const float*)d_in[9];
    const float* W_in_item = (const float*)d_in[10];
    const float* b_in_item = (const float*)d_in[11];
    const float* Wl_rates  = (const float*)d_in[12];
    const float* bl_rates  = (const float*)d_in[13];
    const float* Wr_rates  = (const float*)d_in[14];
    const float* Wl_rated  = (const float*)d_in[15];
    const float* bl_rated  = (const float*)d_in[16];
    const float* Wr_rated  = (const float*)d_in[17];
    const float* Wl_fol    = (const float*)d_in[18];
    const float* bl_fol    = (const float*)d_in[19];
    const float* Wr_fol    = (const float*)d_in[20];
    const float* W_out     = (const float*)d_in[21];
    const float* b_out     = (const float*)d_in[22];
    float* out = (float*)d_out;

    char* w = (char*)d_ws;
    size_t used = 0;
    auto alloc = [&](size_t bytes) -> void* {
        void* p = w + used;
        used += (bytes + 255) & ~(size_t)255;
        return p;
    };
    short* hu_a = (short*)alloc((size_t)NU * HD * 2);
    short* hu_b = (short*)alloc((size_t)NU * HD * 2);
    short* hi_a = (short*)alloc((size_t)NI * HD * 2);
    short* hi_b = (short*)alloc((size_t)NI * HD * 2);

    int* deg_rates  = (int*)alloc((size_t)NI * 4);
    int* off_rates  = (int*)alloc((size_t)(NI + 1) * 4);
    int* cur_rates  = (int*)alloc((size_t)NI * 4);
    int* esrc_rates = (int*)alloc((size_t)NEDGE * 4);
    int* deg_rated  = (int*)alloc((size_t)NU * 4);
    int* off_rated  = (int*)alloc((size_t)(NU + 1) * 4);
    int* cur_rated  = (int*)alloc((size_t)NU * 4);
    int* esrc_rated = (int*)alloc((size_t)NEDGE * 4);
    int* deg_fol    = (int*)alloc((size_t)NU * 4);
    int* off_fol    = (int*)alloc((size_t)(NU + 1) * 4);
    int* cur_fol    = (int*)alloc((size_t)NU * 4);
    int* esrc_fol   = (int*)alloc((size_t)NEDGE * 4);
    int* bsum = (int*)alloc(1024 * 4);
    int* boff = (int*)alloc(1024 * 4);

    short* pWu      = (short*)alloc(8 * 2 * 64 * 8 * 2);
    short* pWi      = (short*)alloc(8 * 4 * 64 * 8 * 2);
    short* pRates0  = (short*)alloc(8 * 8 * 64 * 8 * 2);
    short* pRates1  = (short*)alloc(8 * 8 * 64 * 8 * 2);
    short* pRated0  = (short*)alloc(8 * 8 * 64 * 8 * 2);
    short* pRated1  = (short*)alloc(8 * 8 * 64 * 8 * 2);
    short* pFol0    = (short*)alloc(8 * 4 * 64 * 8 * 2);
    short* pFol1    = (short*)alloc(8 * 4 * 64 * 8 * 2);
    short* pHead    = (short*)alloc(1 * 4 * 64 * 8 * 2);
    float* bSum0    = (float*)alloc(128 * 4);
    float* bSum1    = (float*)alloc(128 * 4);
    if (used > ws_size) return;   // diagnostic signature: output stays zero

    auto build_csr = [&](const int* dstA, const int* srcA, int N, int* deg, int* off,
                         int* cur, int* esrc) {
        hipMemsetAsync(deg, 0, (size_t)N * 4, stream);
        k_hist<<<(NEDGE + 255) / 256, 256, 0, stream>>>(dstA, deg, NEDGE);
        int nb = (N + 1023) / 1024;
        k_block_sums<<<nb, 1024, 0, stream>>>(deg, bsum, N);
        k_scan_bsums<<<1, 1024, 0, stream>>>(bsum, boff, off, nb, N);
        k_scan_write<<<nb, 1024, 0, stream>>>(deg, boff, off, N);
        hipMemcpyAsync(cur, off, (size_t)N * 4, hipMemcpyDeviceToDevice, stream);
        k_fill<<<(NEDGE + 255) / 256, 256, 0, stream>>>(srcA, dstA, cur, esrc, NEDGE);
    };

    build_csr(dst_rates, src_rates, NI, deg_rates, off_rates, cur_rates, esrc_rates);
    build_csr(dst_rated, src_rated, NU, deg_rated, off_rated, cur_rated, esrc_rated);
    build_csr(dst_fol,   src_fol,   NU, deg_fol,   off_fol,   cur_fol,   esrc_fol);

    // ---- weight packing ----
    k_pack<<<16, 64, 0, stream>>>(pWu, W_in_user, nullptr, nullptr, 64, 0, 128);
    k_pack<<<32, 64, 0, stream>>>(pWi, W_in_item, nullptr, nullptr, 128, 0, 128);
    k_pack<<<64, 64, 0, stream>>>(pRates0, Wl_rates,      Wr_rates,      nullptr,       128, 128, 128);
    k_pack<<<64, 64, 0, stream>>>(pRates1, Wl_rates + HH, Wr_rates + HH, nullptr,       128, 128, 128);
    k_pack<<<64, 64, 0, stream>>>(pRated0, Wl_rated,      Wr_rated,      Wr_fol,        128, 128, 128);
    k_pack<<<64, 64, 0, stream>>>(pRated1, Wl_rated + HH, Wr_rated + HH, Wr_fol + HH,   128, 128, 128);
    k_pack<<<32, 64, 0, stream>>>(pFol0, Wl_fol,      nullptr, nullptr, 128, 0, 128);
    k_pack<<<32, 64, 0, stream>>>(pFol1, Wl_fol + HH, nullptr, nullptr, 128, 0, 128);
    k_pack<<<4, 64, 0, stream>>>(pHead, W_out, nullptr, nullptr, 128, 0, 16);
    k_addbias<<<1, 128, 0, stream>>>(bSum0, bl_rated,       bl_fol);
    k_addbias<<<1, 128, 0, stream>>>(bSum1, bl_rated + 128, bl_fol + 128);

    const int gU2 = (NU + 127) / 128;  // k_mm v2 grids
    const int gI2 = (NI + 127) / 128;
    const int gU  = (NU + 63) / 64;    // k_sage grids
    const int gI  = (NI + 63) / 64;

    // ---- input projections (fp32 A) ----
    k_mm<2, true, false, 8><<<gU2, 256, 0, stream>>>(x_user, pWu, b_in_user, hu_a, NU);
    k_mm<4, true, false, 8><<<gI2, 256, 0, stream>>>(x_item, pWi, b_in_item, hi_a, NI);

    // ---- layer 0 (leaky) ----
    k_sage<4, false, true><<<gI, 256, 0, stream>>>(
        hu_a, hi_a, off_rates, esrc_rates, pRates0, bl_rates, hi_b, NI);
    k_sage<4, false, false><<<gU, 256, 0, stream>>>(
        hi_a, hu_a, off_rated, esrc_rated, pRated0, bSum0, hu_b, NU);
    k_sage<0, true, true><<<gU, 256, 0, stream>>>(
        hu_a, nullptr, off_fol, esrc_fol, pFol0, nullptr, hu_b, NU);

    // ---- layer 1 (no leaky) ----
    k_sage<4, false, false><<<gI, 256, 0, stream>>>(
        hu_b, hi_b, off_rates, esrc_rates, pRates1, bl_rates + 128, hi_a, NI);
    k_sage<4, false, false><<<gU, 256, 0, stream>>>(
        hi_b, hu_b, off_rated, esrc_rated, pRated1, bSum1, hu_a, NU);
    k_sage<0, true, false><<<gU, 256, 0, stream>>>(
        hu_b, nullptr, off_fol, esrc_fol, pFol1, nullptr, hu_a, NU);

    // ---- head (fp32 out) ----
    k_mm<4, false, true, 1><<<gU2, 256, 0, stream>>>(hu_a, pHead, b_out, out, NU);
}